// Round 1
// baseline (6877.734 us; speedup 1.0000x reference)
//
#include <hip/hip_runtime.h>
#include <hip/hip_fp16.h>

#define N 4096
#define KX 3072
#define KZ 128
#define NB (N / 64)
#define NTRI (NB * (NB + 1) / 2)

// ---------- storage-type helpers (float or half D matrices) ----------
__device__ __forceinline__ float4 loadRow4(const float* p) { return *(const float4*)p; }
__device__ __forceinline__ float4 loadRow4(const __half* p) {
  __half2 a = *(const __half2*)p;
  __half2 b = *(const __half2*)(p + 2);
  float2 fa = __half22float2(a), fb = __half22float2(b);
  return make_float4(fa.x, fa.y, fb.x, fb.y);
}
__device__ __forceinline__ void storeD(float* p, float v) { *p = v; }
__device__ __forceinline__ void storeD(__half* p, float v) { *p = __float2half(v); }
__device__ __forceinline__ float toF(float v) { return v; }
__device__ __forceinline__ float toF(__half v) { return __half2float(v); }

// ---------- row squared norms ----------
__global__ __launch_bounds__(256) void sqnorm_kernel(const float* __restrict__ X, int K,
                                                     float* __restrict__ sq) {
  int row = blockIdx.x;
  const float4* xr = (const float4*)(X + (size_t)row * K);
  float s = 0.f;
  int n4 = K >> 2;
  for (int i = threadIdx.x; i < n4; i += 256) {
    float4 v = xr[i];
    s += v.x * v.x + v.y * v.y + v.z * v.z + v.w * v.w;
  }
  for (int off = 32; off > 0; off >>= 1) s += __shfl_down(s, off);
  __shared__ float wsum[4];
  int lane = threadIdx.x & 63, w = threadIdx.x >> 6;
  if (lane == 0) wsum[w] = s;
  __syncthreads();
  if (threadIdx.x == 0) {
    float t = 0.f;
    #pragma unroll
    for (int i = 0; i < 4; ++i) t += wsum[i];
    sq[row] = t;
  }
}

// ---------- fused distance GEMM: D = sqrt(relu(sq_i + sq_j - 2*X@X^T)) ----------
// lower-triangular tile enumeration; each block writes tile and its transpose.
template <typename T>
__global__ __launch_bounds__(256) void dist_gemm_kernel(const float* __restrict__ X, int K,
                                                        const float* __restrict__ sq,
                                                        T* __restrict__ D) {
  int t = blockIdx.x;
  int br = (int)((sqrtf(8.0f * (float)t + 1.0f) - 1.0f) * 0.5f);
  while ((br + 1) * (br + 2) / 2 <= t) ++br;
  while (br * (br + 1) / 2 > t) --br;
  int bc = t - br * (br + 1) / 2;
  int i0 = br * 64, j0 = bc * 64;

  __shared__ float As[32][68];
  __shared__ float Bs[32][68];

  int tid = threadIdx.x;
  int tx = tid & 15, ty = tid >> 4;

  float acc[4][4] = {};

  for (int k0 = 0; k0 < K; k0 += 32) {
    #pragma unroll
    for (int u = 0; u < 2; ++u) {
      int f = tid + u * 256;   // 0..511
      int m = f >> 3;          // 0..63
      int kc = (f & 7) * 4;    // 0..28
      float4 a = *(const float4*)(X + (size_t)(i0 + m) * K + k0 + kc);
      As[kc + 0][m] = a.x; As[kc + 1][m] = a.y; As[kc + 2][m] = a.z; As[kc + 3][m] = a.w;
      float4 b = *(const float4*)(X + (size_t)(j0 + m) * K + k0 + kc);
      Bs[kc + 0][m] = b.x; Bs[kc + 1][m] = b.y; Bs[kc + 2][m] = b.z; Bs[kc + 3][m] = b.w;
    }
    __syncthreads();
    #pragma unroll
    for (int kk = 0; kk < 32; ++kk) {
      float4 a = *(const float4*)&As[kk][ty * 4];
      float4 b = *(const float4*)&Bs[kk][tx * 4];
      float av[4] = {a.x, a.y, a.z, a.w};
      float bv[4] = {b.x, b.y, b.z, b.w};
      #pragma unroll
      for (int i = 0; i < 4; ++i)
        #pragma unroll
        for (int j = 0; j < 4; ++j)
          acc[i][j] = fmaf(av[i], bv[j], acc[i][j]);
    }
    __syncthreads();
  }

  #pragma unroll
  for (int i = 0; i < 4; ++i) {
    int gi = i0 + ty * 4 + i;
    float sqi = sq[gi];
    #pragma unroll
    for (int j = 0; j < 4; ++j) {
      int gj = j0 + tx * 4 + j;
      float d2 = sqi + sq[gj] - 2.0f * acc[i][j];
      float d = sqrtf(fmaxf(d2, 0.0f));
      storeD(&D[(size_t)gi * N + gj], d);
      storeD(&D[(size_t)gj * N + gi], d);
    }
  }
}

// ---------- MST (exact replication of the reference scan) ----------
// block 0 -> Dx, block 1 -> Dz. 1024 threads, 4 consecutive nodes per thread.
template <typename T>
__global__ __launch_bounds__(1024) void mst_kernel(const T* __restrict__ Dx,
                                                   const T* __restrict__ Dz,
                                                   int2* __restrict__ ex,
                                                   int2* __restrict__ ez) {
  const T* __restrict__ D = (blockIdx.x == 0) ? Dx : Dz;
  int2* __restrict__ edges = (blockIdx.x == 0) ? ex : ez;
  const float INF = __builtin_inff();

  int tid = threadIdx.x;
  int base = tid * 4;
  int lane = tid & 63;

  float md[4];
  int par[4] = {0, 0, 0, 0};
  {
    float4 r = loadRow4(D + base);
    md[0] = r.x; md[1] = r.y; md[2] = r.z; md[3] = r.w;
    if (tid == 0) md[0] = INF;  // node 0 starts in tree
  }

  __shared__ float swv[2][16];
  __shared__ int swi[2][16];

  for (int step = 0; step < N - 1; ++step) {
    // thread-local argmin (lowest index on ties)
    float bv = md[0]; int bi = base;
    #pragma unroll
    for (int q = 1; q < 4; ++q)
      if (md[q] < bv) { bv = md[q]; bi = base + q; }
    // wave butterfly argmin
    #pragma unroll
    for (int m = 32; m; m >>= 1) {
      float ov = __shfl_xor(bv, m);
      int oi = __shfl_xor(bi, m);
      if (ov < bv || (ov == bv && oi < bi)) { bv = ov; bi = oi; }
    }
    int p = step & 1;
    if (lane == 0) { swv[p][tid >> 6] = bv; swi[p][tid >> 6] = bi; }
    __syncthreads();
    // every wave redundantly reduces the 16 wave minima -> no broadcast barrier
    bv = swv[p][lane & 15]; bi = swi[p][lane & 15];
    #pragma unroll
    for (int m = 8; m; m >>= 1) {
      float ov = __shfl_xor(bv, m);
      int oi = __shfl_xor(bi, m);
      if (ov < bv || (ov == bv && oi < bi)) { bv = ov; bi = oi; }
    }
    int j = bi;

    // record edge with parent BEFORE this step's updates (matches reference order)
    if ((j >> 2) == tid) edges[step] = make_int2(par[j & 3], j);

    float4 r = loadRow4(D + (size_t)j * N + base);
    float rv[4] = {r.x, r.y, r.z, r.w};
    #pragma unroll
    for (int q = 0; q < 4; ++q)
      if (rv[q] < md[q]) { md[q] = rv[q]; par[q] = j; }
    if ((j >> 2) == tid) md[j & 3] = INF;  // applied after the min-update, like .at[j].set(inf)
  }
}

// ---------- final loss ----------
template <typename T>
__global__ __launch_bounds__(1024) void loss_kernel(const T* __restrict__ Dx,
                                                    const T* __restrict__ Dz,
                                                    const int2* __restrict__ ex,
                                                    const int2* __restrict__ ez,
                                                    float* __restrict__ out) {
  int tid = threadIdx.x;
  float s = 0.f;
  const int M = N - 1;
  for (int e = tid; e < 2 * M; e += 1024) {
    int2 uv = (e < M) ? ex[e] : ez[e - M];
    size_t off = (size_t)uv.x * N + uv.y;
    float dx = toF(Dx[off]);
    float dz = toF(Dz[off]);
    float d = dx - dz;
    s += d * d;
  }
  for (int off = 32; off > 0; off >>= 1) s += __shfl_down(s, off);
  __shared__ float wsum[16];
  int lane = tid & 63, w = tid >> 6;
  if (lane == 0) wsum[w] = s;
  __syncthreads();
  if (tid == 0) {
    float t = 0.f;
    #pragma unroll
    for (int i = 0; i < 16; ++i) t += wsum[i];
    out[0] = 0.5f * t;
  }
}

// ---------- launch ----------
template <typename T>
static void launch_all(const float* x, const float* z, char* ws, float* out,
                       hipStream_t stream) {
  T* Dx = (T*)ws;
  T* Dz = Dx + (size_t)N * N;
  float* sqx = (float*)(Dz + (size_t)N * N);
  float* sqz = sqx + N;
  int2* ex = (int2*)(sqz + N);
  int2* ez = ex + (N - 1);

  sqnorm_kernel<<<N, 256, 0, stream>>>(x, KX, sqx);
  sqnorm_kernel<<<N, 256, 0, stream>>>(z, KZ, sqz);
  dist_gemm_kernel<T><<<NTRI, 256, 0, stream>>>(x, KX, sqx, Dx);
  dist_gemm_kernel<T><<<NTRI, 256, 0, stream>>>(z, KZ, sqz, Dz);
  mst_kernel<T><<<2, 1024, 0, stream>>>(Dx, Dz, ex, ez);
  loss_kernel<T><<<1, 1024, 0, stream>>>(Dx, Dz, ex, ez, out);
}

extern "C" void kernel_launch(void* const* d_in, const int* in_sizes, int n_in,
                              void* d_out, int out_size, void* d_ws, size_t ws_size,
                              hipStream_t stream) {
  const float* x = (const float*)d_in[0];
  const float* z = (const float*)d_in[1];
  float* out = (float*)d_out;
  char* ws = (char*)d_ws;

  size_t need_f32 = (size_t)2 * N * N * sizeof(float) + 2 * N * sizeof(float)
                  + (size_t)2 * (N - 1) * sizeof(int2);
  if (ws_size >= need_f32) {
    launch_all<float>(x, z, ws, out, stream);
  } else {
    launch_all<__half>(x, z, ws, out, stream);
  }
}